// Round 1
// baseline (3168.358 us; speedup 1.0000x reference)
//
#include <hip/hip_runtime.h>
#include <math.h>

#define H 4
#define C 64
#define HC 256
#define NEG 0.2f

// monotone float->int key for atomicMax on signed ints
__device__ __forceinline__ int fkey(float f) {
    int i = __float_as_int(f);
    return i >= 0 ? i : (i ^ 0x7FFFFFFF);
}
__device__ __forceinline__ float funkey(int k) {
    int i = k >= 0 ? k : (k ^ 0x7FFFFFFF);
    return __int_as_float(i);
}

// init: amax keys to -inf-key; sum edge_attr for mean; K[h] = dot(lin_edge_w[h], att_edge[h])
__global__ void init_kernel(const float* __restrict__ edge_attr,
                            const float* __restrict__ lin_edge_w,
                            const float* __restrict__ att_edge,
                            int* __restrict__ amaxI, float* __restrict__ mean_acc,
                            float* __restrict__ Kh, int Nn, int Ee) {
    int gid = blockIdx.x * blockDim.x + threadIdx.x;
    int stride = gridDim.x * blockDim.x;
    for (int i = gid; i < Nn * H; i += stride) amaxI[i] = (int)0x80000000;
    float s = 0.f;
    for (int i = gid; i < Ee; i += stride) s += edge_attr[i];
    __shared__ float red[256];
    red[threadIdx.x] = s;
    __syncthreads();
    for (int off = 128; off; off >>= 1) {
        if (threadIdx.x < off) red[threadIdx.x] += red[threadIdx.x + off];
        __syncthreads();
    }
    if (threadIdx.x == 0) atomicAdd(mean_acc, red[0]);
    if (gid < H) {
        float k = 0.f;
        for (int c = 0; c < C; ++c) k += lin_edge_w[gid * C + c] * att_edge[gid * C + c];
        Kh[gid] = k;
    }
}

// h = x @ W  (W column t held in 64 registers per thread), fused a_src/a_dst
__global__ __launch_bounds__(256) void gemm_kernel(
    const float* __restrict__ x, const float* __restrict__ W,
    const float* __restrict__ att_src, const float* __restrict__ att_dst,
    float* __restrict__ h, float* __restrict__ a_src, float* __restrict__ a_dst,
    int Nn) {
    int t = threadIdx.x;
    float w[64];
#pragma unroll
    for (int k = 0; k < 64; ++k) w[k] = W[k * HC + t];  // coalesced per k
    float as = att_src[t], ad = att_dst[t];
    __shared__ float xs[64];
    int lane = t & 63, wv = t >> 6;  // wave index == head index
    for (int n = blockIdx.x; n < Nn; n += gridDim.x) {
        __syncthreads();
        if (t < 16) ((float4*)xs)[t] = ((const float4*)(x + (size_t)n * 64))[t];
        __syncthreads();
        float acc = 0.f;
#pragma unroll
        for (int k = 0; k < 64; ++k) acc += xs[k] * w[k];
        h[(size_t)n * HC + t] = acc;
        float vs = acc * as, vd = acc * ad;
#pragma unroll
        for (int off = 32; off; off >>= 1) {
            vs += __shfl_down(vs, off);
            vd += __shfl_down(vd, off);
        }
        if (lane == 0) { a_src[n * H + wv] = vs; a_dst[n * H + wv] = vd; }
    }
}

// per-edge attention logits (leaky-relu'd), stored; atomic segment-max by dst
__global__ void logits_kernel(const int* __restrict__ ei,
                              const float* __restrict__ edge_attr,
                              const float* __restrict__ a_src,
                              const float* __restrict__ a_dst,
                              const float* __restrict__ mean_acc,
                              const float* __restrict__ Kh,
                              float* __restrict__ al, int* __restrict__ amaxI,
                              int Nn, int Ee) {
    int i = blockIdx.x * blockDim.x + threadIdx.x;
    int tot = Ee + Nn;
    if (i >= tot) return;
    int src, dst;
    float ea;
    if (i < Ee) {
        src = ei[i];
        dst = ei[Ee + i];
        ea = edge_attr[i];
    } else {  // self-loop, fill_value = mean(edge_attr)
        src = dst = i - Ee;
        ea = mean_acc[0] * (1.0f / (float)Ee);
    }
    float4 s4 = ((const float4*)a_src)[src];
    float4 d4 = ((const float4*)a_dst)[dst];
    float4 k4 = ((const float4*)Kh)[0];
    float v[4];
    v[0] = s4.x + d4.x + ea * k4.x;
    v[1] = s4.y + d4.y + ea * k4.y;
    v[2] = s4.z + d4.z + ea * k4.z;
    v[3] = s4.w + d4.w + ea * k4.w;
#pragma unroll
    for (int hh = 0; hh < H; ++hh) {
        float lv = v[hh];
        lv = lv > 0.f ? lv : NEG * lv;
        v[hh] = lv;
        atomicMax(&amaxI[dst * H + hh], fkey(lv));
    }
    ((float4*)al)[i] = make_float4(v[0], v[1], v[2], v[3]);
}

// one wave per edge: w = exp(al - amax[dst]); asum += w; accum[dst] += w * h[src]
__global__ __launch_bounds__(256) void scatter_kernel(
    const int* __restrict__ ei, const float* __restrict__ h,
    const float* __restrict__ al, const int* __restrict__ amaxI,
    float* __restrict__ asum, float* __restrict__ accum, int Nn, int Ee) {
    int lane = threadIdx.x & 63;
    int e = blockIdx.x * 4 + (threadIdx.x >> 6);
    int tot = Ee + Nn;
    if (e >= tot) return;
    int src, dst;
    if (e < Ee) {
        src = ei[e];
        dst = ei[Ee + e];
    } else {
        src = dst = e - Ee;
    }
    int head = lane >> 4;
    float a = al[(size_t)e * H + head];
    float am = funkey(amaxI[dst * H + head]);
    float wgt = __expf(a - am);
    if ((lane & 15) == 0) unsafeAtomicAdd(&asum[dst * H + head], wgt);
    float4 hv = ((const float4*)h)[(size_t)src * 64 + lane];
    float* ap = accum + (size_t)dst * HC + lane * 4;
    unsafeAtomicAdd(ap + 0, wgt * hv.x);
    unsafeAtomicAdd(ap + 1, wgt * hv.y);
    unsafeAtomicAdd(ap + 2, wgt * hv.z);
    unsafeAtomicAdd(ap + 3, wgt * hv.w);
}

// out = relu(mean_h(accum/asum) + bias) + x
__global__ void epilogue_kernel(const float* __restrict__ accum,
                                const float* __restrict__ asum,
                                const float* __restrict__ bias,
                                const float* __restrict__ x,
                                float* __restrict__ out, int Nn) {
    int i = blockIdx.x * blockDim.x + threadIdx.x;
    if (i >= Nn * 64) return;
    int n = i >> 6, c = i & 63;
    float s = 0.f;
#pragma unroll
    for (int hh = 0; hh < H; ++hh)
        s += accum[(size_t)n * HC + hh * 64 + c] / (asum[n * H + hh] + 1e-16f);
    s = s * 0.25f + bias[c];
    out[i] = fmaxf(s, 0.f) + x[i];
}

extern "C" void kernel_launch(void* const* d_in, const int* in_sizes, int n_in,
                              void* d_out, int out_size, void* d_ws, size_t ws_size,
                              hipStream_t stream) {
    const float* x = (const float*)d_in[0];
    const int* ei = (const int*)d_in[1];
    const float* edge_attr = (const float*)d_in[2];
    const float* W = (const float*)d_in[3];
    const float* att_src = (const float*)d_in[4];
    const float* att_dst = (const float*)d_in[5];
    const float* lin_edge_w = (const float*)d_in[6];
    const float* att_edge = (const float*)d_in[7];
    const float* bias = (const float*)d_in[8];
    float* out = (float*)d_out;
    int Nn = in_sizes[0] / 64;
    int Ee = in_sizes[1] / 2;
    int tot = Ee + Nn;

    char* p = (char*)d_ws;
    size_t o = 0;
    auto alloc = [&](size_t bytes) -> char* {
        char* r = p + o;
        o += (bytes + 255) & ~(size_t)255;
        return r;
    };
    float* accum = (float*)alloc((size_t)Nn * HC * 4);  // [N,H,C] unnormalized msgs
    float* asum = (float*)alloc((size_t)Nn * H * 4);    // [N,H] exp-sums
    float* mean_acc = (float*)alloc(256);               // edge_attr sum
    size_t zero_bytes = o;                              // everything above needs 0-init
    float* Kh = (float*)alloc(256);                     // [H] per-head edge coeff
    float* h = (float*)alloc((size_t)Nn * HC * 4);      // [N,H,C]
    float* a_src = (float*)alloc((size_t)Nn * H * 4);
    float* a_dst = (float*)alloc((size_t)Nn * H * 4);
    int* amaxI = (int*)alloc((size_t)Nn * H * 4);       // segment-max keys
    float* al = (float*)alloc((size_t)tot * H * 4);     // per-edge leaky logits
    (void)ws_size;

    hipMemsetAsync(d_ws, 0, zero_bytes, stream);
    init_kernel<<<1024, 256, 0, stream>>>(edge_attr, lin_edge_w, att_edge, amaxI,
                                          mean_acc, Kh, Nn, Ee);
    gemm_kernel<<<2048, 256, 0, stream>>>(x, W, att_src, att_dst, h, a_src, a_dst, Nn);
    logits_kernel<<<(tot + 255) / 256, 256, 0, stream>>>(ei, edge_attr, a_src, a_dst,
                                                         mean_acc, Kh, al, amaxI, Nn, Ee);
    scatter_kernel<<<(tot + 3) / 4, 256, 0, stream>>>(ei, h, al, amaxI, asum, accum, Nn, Ee);
    epilogue_kernel<<<(Nn * 64 + 255) / 256, 256, 0, stream>>>(accum, asum, bias, x, out, Nn);
}

// Round 2
// 420.813 us; speedup vs baseline: 7.5291x; 7.5291x over previous
//
#include <hip/hip_runtime.h>
#include <math.h>

#define H 4
#define C 64
#define HC 256
#define NEG 0.2f

// ---------------------------------------------------------------------------
// init: counts[i]=1 (self-loop), partial sum of edge_attr, Kh[h]=dot(lin_edge_w[h],att_edge[h])
__global__ void init_kernel(const float* __restrict__ edge_attr,
                            const float* __restrict__ lin_edge_w,
                            const float* __restrict__ att_edge,
                            int* __restrict__ counts, float* __restrict__ mean_acc,
                            float* __restrict__ Kh, int Nn, int Ee) {
    int gid = blockIdx.x * blockDim.x + threadIdx.x;
    int stride = gridDim.x * blockDim.x;
    for (int i = gid; i < Nn; i += stride) counts[i] = 1;  // self-loop
    float s = 0.f;
    for (int i = gid; i < Ee; i += stride) s += edge_attr[i];
    __shared__ float red[256];
    red[threadIdx.x] = s;
    __syncthreads();
    for (int off = 128; off; off >>= 1) {
        if (threadIdx.x < off) red[threadIdx.x] += red[threadIdx.x + off];
        __syncthreads();
    }
    if (threadIdx.x == 0) atomicAdd(mean_acc, red[0]);
    if (gid < H) {
        float k = 0.f;
        for (int c = 0; c < C; ++c) k += lin_edge_w[gid * C + c] * att_edge[gid * C + c];
        Kh[gid] = k;
    }
}

// histogram of dst over real edges (self-loops pre-counted by init)
__global__ void hist_kernel(const int* __restrict__ ei, int* __restrict__ counts, int Ee) {
    int i = blockIdx.x * blockDim.x + threadIdx.x;
    if (i < Ee) atomicAdd(&counts[ei[Ee + i]], 1);
}

// single-block exclusive scan of counts[Nn] -> off[Nn+1], cursor copy
__global__ __launch_bounds__(1024) void scan_kernel(const int* __restrict__ counts,
                                                    int* __restrict__ off,
                                                    int* __restrict__ cursor, int Nn) {
    __shared__ int buf[2][1024];
    int tid = threadIdx.x;
    int carry = 0;
    for (int base = 0; base < Nn; base += 1024) {
        int v = (base + tid < Nn) ? counts[base + tid] : 0;
        int pp = 0;
        buf[0][tid] = v;
        __syncthreads();
        for (int d = 1; d < 1024; d <<= 1) {
            int nv = buf[pp][tid];
            if (tid >= d) nv += buf[pp][tid - d];
            buf[pp ^ 1][tid] = nv;
            pp ^= 1;
            __syncthreads();
        }
        int incl = buf[pp][tid];
        int excl = carry + incl - v;
        if (base + tid < Nn) {
            off[base + tid] = excl;
            cursor[base + tid] = excl;
        }
        int total = buf[pp][1023];
        __syncthreads();  // before next chunk overwrites buf
        carry += total;
    }
    if (tid == 0) off[Nn] = carry;
}

// ---------------------------------------------------------------------------
// h = x @ W (W column t in registers), fused per-head a_src/a_dst dot products
__global__ __launch_bounds__(256) void gemm_kernel(
    const float* __restrict__ x, const float* __restrict__ W,
    const float* __restrict__ att_src, const float* __restrict__ att_dst,
    float* __restrict__ h, float* __restrict__ a_src, float* __restrict__ a_dst,
    int Nn) {
    int t = threadIdx.x;
    float w[64];
#pragma unroll
    for (int k = 0; k < 64; ++k) w[k] = W[k * HC + t];
    float as = att_src[t], ad = att_dst[t];
    __shared__ float xs[64];
    int lane = t & 63, wv = t >> 6;  // wave index == head index
    for (int n = blockIdx.x; n < Nn; n += gridDim.x) {
        __syncthreads();
        if (t < 16) ((float4*)xs)[t] = ((const float4*)(x + (size_t)n * 64))[t];
        __syncthreads();
        float acc = 0.f;
#pragma unroll
        for (int k = 0; k < 64; ++k) acc += xs[k] * w[k];
        h[(size_t)n * HC + t] = acc;
        float vs = acc * as, vd = acc * ad;
#pragma unroll
        for (int off = 32; off; off >>= 1) {
            vs += __shfl_down(vs, off);
            vd += __shfl_down(vd, off);
        }
        if (lane == 0) { a_src[n * H + wv] = vs; a_dst[n * H + wv] = vd; }
    }
}

// ---------------------------------------------------------------------------
// fused logits + bucket-by-dst: srcS[pos], alS[pos] = leaky(a_src+a_dst+ea*K)
__global__ void sortscatter_kernel(const int* __restrict__ ei,
                                   const float* __restrict__ edge_attr,
                                   const float* __restrict__ a_src,
                                   const float* __restrict__ a_dst,
                                   const float* __restrict__ mean_acc,
                                   const float* __restrict__ Kh,
                                   int* __restrict__ cursor,
                                   int* __restrict__ srcS, float* __restrict__ alS,
                                   int Nn, int Ee) {
    int i = blockIdx.x * blockDim.x + threadIdx.x;
    int tot = Ee + Nn;
    if (i >= tot) return;
    int src, dst;
    float ea;
    if (i < Ee) {
        src = ei[i];
        dst = ei[Ee + i];
        ea = edge_attr[i];
    } else {  // self-loop, fill_value = mean(edge_attr)
        src = dst = i - Ee;
        ea = mean_acc[0] * (1.0f / (float)Ee);
    }
    float4 s4 = ((const float4*)a_src)[src];
    float4 d4 = ((const float4*)a_dst)[dst];
    float4 k4 = ((const float4*)Kh)[0];
    float4 v;
    v.x = s4.x + d4.x + ea * k4.x;
    v.y = s4.y + d4.y + ea * k4.y;
    v.z = s4.z + d4.z + ea * k4.z;
    v.w = s4.w + d4.w + ea * k4.w;
    v.x = v.x > 0.f ? v.x : NEG * v.x;
    v.y = v.y > 0.f ? v.y : NEG * v.y;
    v.z = v.z > 0.f ? v.z : NEG * v.z;
    v.w = v.w > 0.f ? v.w : NEG * v.w;
    int pos = atomicAdd(&cursor[dst], 1);
    srcS[pos] = src;
    ((float4*)alS)[pos] = v;
}

// ---------------------------------------------------------------------------
// one wave per dst node: local softmax-max, exp-sum, weighted gather of h[src],
// normalize, head-mean, bias, relu, residual -> out. No atomics.
__global__ __launch_bounds__(256) void aggregate_kernel(
    const int* __restrict__ off, const int* __restrict__ srcS,
    const float* __restrict__ alS, const float* __restrict__ h,
    const float* __restrict__ bias, const float* __restrict__ x,
    float* __restrict__ out, int Nn) {
    int lane = threadIdx.x & 63;
    int n = blockIdx.x * 4 + (threadIdx.x >> 6);
    if (n >= Nn) return;
    int o0 = off[n], o1 = off[n + 1];
    int deg = o1 - o0;

    // phase 1: per-head max over this node's bucket (lane i handles edge i>>2, head i&3)
    int sub = lane >> 2, hh = lane & 3;
    float mx = -INFINITY;
    for (int i = sub; i < deg; i += 16)
        mx = fmaxf(mx, alS[(size_t)(o0 + i) * 4 + hh]);
    mx = fmaxf(mx, __shfl_xor(mx, 4));
    mx = fmaxf(mx, __shfl_xor(mx, 8));
    mx = fmaxf(mx, __shfl_xor(mx, 16));
    mx = fmaxf(mx, __shfl_xor(mx, 32));
    int head = lane >> 4;
    float m0 = __shfl(mx, 0), m1 = __shfl(mx, 1), m2 = __shfl(mx, 2), m3 = __shfl(mx, 3);
    float mh = head == 0 ? m0 : head == 1 ? m1 : head == 2 ? m2 : m3;

    // phase 2: exp-weight + gather h rows (1KB coalesced per edge)
    float4 acc = make_float4(0.f, 0.f, 0.f, 0.f);
    float swgt = 0.f;
    int src_n = 0;
    float a_n = 0.f;
    if (deg > 0) {
        src_n = srcS[o0];
        a_n = alS[(size_t)o0 * 4 + head];
    }
#pragma unroll 2
    for (int i = 0; i < deg; ++i) {
        int src = src_n;
        float a = a_n;
        if (i + 1 < deg) {  // prefetch next edge's metadata
            src_n = srcS[o0 + i + 1];
            a_n = alS[(size_t)(o0 + i + 1) * 4 + head];
        }
        float wgt = __expf(a - mh);
        swgt += wgt;
        float4 hv = ((const float4*)h)[(size_t)src * 64 + lane];
        acc.x += wgt * hv.x;
        acc.y += wgt * hv.y;
        acc.z += wgt * hv.z;
        acc.w += wgt * hv.w;
    }
    float inv = 1.f / (swgt + 1e-16f);
    acc.x *= inv; acc.y *= inv; acc.z *= inv; acc.w *= inv;

    // head-mean: sum lanes {l, l^16, l^32, l^48} (same channels, different heads)
    acc.x += __shfl_xor(acc.x, 16);
    acc.y += __shfl_xor(acc.y, 16);
    acc.z += __shfl_xor(acc.z, 16);
    acc.w += __shfl_xor(acc.w, 16);
    acc.x += __shfl_xor(acc.x, 32);
    acc.y += __shfl_xor(acc.y, 32);
    acc.z += __shfl_xor(acc.z, 32);
    acc.w += __shfl_xor(acc.w, 32);
    if (lane < 16) {
        float4 b = ((const float4*)bias)[lane];
        float4 xv = ((const float4*)x)[(size_t)n * 16 + lane];
        float4 o;
        o.x = fmaxf(acc.x * 0.25f + b.x, 0.f) + xv.x;
        o.y = fmaxf(acc.y * 0.25f + b.y, 0.f) + xv.y;
        o.z = fmaxf(acc.z * 0.25f + b.z, 0.f) + xv.z;
        o.w = fmaxf(acc.w * 0.25f + b.w, 0.f) + xv.w;
        ((float4*)out)[(size_t)n * 16 + lane] = o;
    }
}

// ---------------------------------------------------------------------------
extern "C" void kernel_launch(void* const* d_in, const int* in_sizes, int n_in,
                              void* d_out, int out_size, void* d_ws, size_t ws_size,
                              hipStream_t stream) {
    const float* x = (const float*)d_in[0];
    const int* ei = (const int*)d_in[1];
    const float* edge_attr = (const float*)d_in[2];
    const float* W = (const float*)d_in[3];
    const float* att_src = (const float*)d_in[4];
    const float* att_dst = (const float*)d_in[5];
    const float* lin_edge_w = (const float*)d_in[6];
    const float* att_edge = (const float*)d_in[7];
    const float* bias = (const float*)d_in[8];
    float* out = (float*)d_out;
    int Nn = in_sizes[0] / 64;
    int Ee = in_sizes[1] / 2;
    int tot = Ee + Nn;

    char* p = (char*)d_ws;
    size_t o = 0;
    auto alloc = [&](size_t bytes) -> char* {
        char* r = p + o;
        o += (bytes + 255) & ~(size_t)255;
        return r;
    };
    float* mean_acc = (float*)alloc(256);               // zeroed below
    float* Kh = (float*)alloc(256);                     // [H]
    int* counts = (int*)alloc((size_t)Nn * 4);          // [N] in-degree (incl self)
    int* off = (int*)alloc((size_t)(Nn + 1) * 4);       // [N+1] CSR offsets
    int* cursor = (int*)alloc((size_t)Nn * 4);          // [N] bucket cursors
    int* srcS = (int*)alloc((size_t)tot * 4);           // [tot] src sorted by dst
    float* alS = (float*)alloc((size_t)tot * H * 4);    // [tot][H] logits sorted by dst
    float* h = (float*)alloc((size_t)Nn * HC * 4);      // [N,H,C]
    float* a_src = (float*)alloc((size_t)Nn * H * 4);
    float* a_dst = (float*)alloc((size_t)Nn * H * 4);
    (void)ws_size;

    hipMemsetAsync(mean_acc, 0, 256, stream);
    init_kernel<<<512, 256, 0, stream>>>(edge_attr, lin_edge_w, att_edge, counts,
                                         mean_acc, Kh, Nn, Ee);
    hist_kernel<<<(Ee + 255) / 256, 256, 0, stream>>>(ei, counts, Ee);
    gemm_kernel<<<2048, 256, 0, stream>>>(x, W, att_src, att_dst, h, a_src, a_dst, Nn);
    scan_kernel<<<1, 1024, 0, stream>>>(counts, off, cursor, Nn);
    sortscatter_kernel<<<(tot + 255) / 256, 256, 0, stream>>>(
        ei, edge_attr, a_src, a_dst, mean_acc, Kh, cursor, srcS, alS, Nn, Ee);
    aggregate_kernel<<<(Nn + 3) / 4, 256, 0, stream>>>(off, srcS, alS, h, bias, x, out, Nn);
}

// Round 3
// 302.153 us; speedup vs baseline: 10.4859x; 1.3927x over previous
//
#include <hip/hip_runtime.h>
#include <hip/hip_fp16.h>
#include <math.h>

#define H 4
#define C 64
#define HC 256
#define NEG 0.2f

// ---------------------------------------------------------------------------
// init: histogram dst (counts pre-zeroed by memset; self-loop +1 folded into
// the scan), partial sum of edge_attr, Kh[h] = dot(lin_edge_w[h], att_edge[h])
__global__ void init_kernel(const int* __restrict__ ei,
                            const float* __restrict__ edge_attr,
                            const float* __restrict__ lin_edge_w,
                            const float* __restrict__ att_edge,
                            int* __restrict__ counts, float* __restrict__ mean_acc,
                            float* __restrict__ Kh, int Ee) {
    int gid = blockIdx.x * blockDim.x + threadIdx.x;
    int stride = gridDim.x * blockDim.x;
    float s = 0.f;
    for (int i = gid; i < Ee; i += stride) {
        s += edge_attr[i];
        atomicAdd(&counts[ei[Ee + i]], 1);
    }
    __shared__ float red[256];
    red[threadIdx.x] = s;
    __syncthreads();
    for (int off = 128; off; off >>= 1) {
        if (threadIdx.x < off) red[threadIdx.x] += red[threadIdx.x + off];
        __syncthreads();
    }
    if (threadIdx.x == 0) atomicAdd(mean_acc, red[0]);
    if (gid < H) {
        float k = 0.f;
        for (int c = 0; c < C; ++c) k += lin_edge_w[gid * C + c] * att_edge[gid * C + c];
        Kh[gid] = k;
    }
}

// ---------------------------------------------------------------------------
// hierarchical scan of (counts[i] + 1) over Nn elements, 256/block
// S1: per-block sums
__global__ __launch_bounds__(256) void scan1_kernel(const int* __restrict__ counts,
                                                    int* __restrict__ blockSums, int Nn) {
    int idx = blockIdx.x * 256 + threadIdx.x;
    int v = (idx < Nn) ? counts[idx] + 1 : 0;
#pragma unroll
    for (int off = 32; off; off >>= 1) v += __shfl_down(v, off);
    __shared__ int ws[4];
    if ((threadIdx.x & 63) == 0) ws[threadIdx.x >> 6] = v;
    __syncthreads();
    if (threadIdx.x == 0) blockSums[blockIdx.x] = ws[0] + ws[1] + ws[2] + ws[3];
}

// S2: exclusive scan of blockSums (numBlocks <= 256), one block
__global__ __launch_bounds__(256) void scan2_kernel(int* __restrict__ blockSums,
                                                    int* __restrict__ blockOff,
                                                    int* __restrict__ off,
                                                    int numBlocks, int Nn) {
    __shared__ int buf[2][256];
    int t = threadIdx.x;
    int v = (t < numBlocks) ? blockSums[t] : 0;
    buf[0][t] = v;
    __syncthreads();
    int pp = 0;
#pragma unroll
    for (int d = 1; d < 256; d <<= 1) {
        int nv = buf[pp][t];
        if (t >= d) nv += buf[pp][t - d];
        buf[pp ^ 1][t] = nv;
        pp ^= 1;
        __syncthreads();
    }
    int incl = buf[pp][t];
    if (t < numBlocks) blockOff[t] = incl - v;
    if (t == 255) off[Nn] = incl;  // grand total
}

// S3: local exclusive scan of 256 + block offset -> off, cursor
__global__ __launch_bounds__(256) void scan3_kernel(const int* __restrict__ counts,
                                                    const int* __restrict__ blockOff,
                                                    int* __restrict__ off,
                                                    int* __restrict__ cursor, int Nn) {
    __shared__ int buf[2][256];
    int t = threadIdx.x;
    int idx = blockIdx.x * 256 + t;
    int v = (idx < Nn) ? counts[idx] + 1 : 0;
    buf[0][t] = v;
    __syncthreads();
    int pp = 0;
#pragma unroll
    for (int d = 1; d < 256; d <<= 1) {
        int nv = buf[pp][t];
        if (t >= d) nv += buf[pp][t - d];
        buf[pp ^ 1][t] = nv;
        pp ^= 1;
        __syncthreads();
    }
    if (idx < Nn) {
        int excl = blockOff[blockIdx.x] + buf[pp][t] - v;
        off[idx] = excl;
        cursor[idx] = excl;
    }
}

// ---------------------------------------------------------------------------
// h = x @ W (W column t in registers), fused per-head a_src/a_dst dots; h -> fp16
__global__ __launch_bounds__(256) void gemm_kernel(
    const float* __restrict__ x, const float* __restrict__ W,
    const float* __restrict__ att_src, const float* __restrict__ att_dst,
    __half* __restrict__ h, float* __restrict__ a_src, float* __restrict__ a_dst,
    int Nn) {
    int t = threadIdx.x;
    float w[64];
#pragma unroll
    for (int k = 0; k < 64; ++k) w[k] = W[k * HC + t];
    float as = att_src[t], ad = att_dst[t];
    __shared__ float xs[64];
    int lane = t & 63, wv = t >> 6;  // wave index == head index
    for (int n = blockIdx.x; n < Nn; n += gridDim.x) {
        __syncthreads();
        if (t < 16) ((float4*)xs)[t] = ((const float4*)(x + (size_t)n * 64))[t];
        __syncthreads();
        float acc = 0.f;
#pragma unroll
        for (int k = 0; k < 64; ++k) acc += xs[k] * w[k];
        h[(size_t)n * HC + t] = __float2half(acc);
        float vs = acc * as, vd = acc * ad;
#pragma unroll
        for (int off = 32; off; off >>= 1) {
            vs += __shfl_down(vs, off);
            vd += __shfl_down(vd, off);
        }
        if (lane == 0) { a_src[n * H + wv] = vs; a_dst[n * H + wv] = vd; }
    }
}

// ---------------------------------------------------------------------------
// fused logits + bucket-by-dst: srcS[pos], alS[pos] = leaky(a_src+a_dst+ea*K)
__global__ void sortscatter_kernel(const int* __restrict__ ei,
                                   const float* __restrict__ edge_attr,
                                   const float* __restrict__ a_src,
                                   const float* __restrict__ a_dst,
                                   const float* __restrict__ mean_acc,
                                   const float* __restrict__ Kh,
                                   int* __restrict__ cursor,
                                   int* __restrict__ srcS, float* __restrict__ alS,
                                   int Nn, int Ee) {
    int i = blockIdx.x * blockDim.x + threadIdx.x;
    int tot = Ee + Nn;
    if (i >= tot) return;
    int src, dst;
    float ea;
    if (i < Ee) {
        src = ei[i];
        dst = ei[Ee + i];
        ea = edge_attr[i];
    } else {  // self-loop, fill_value = mean(edge_attr)
        src = dst = i - Ee;
        ea = mean_acc[0] * (1.0f / (float)Ee);
    }
    float4 s4 = ((const float4*)a_src)[src];
    float4 d4 = ((const float4*)a_dst)[dst];
    float4 k4 = ((const float4*)Kh)[0];
    float4 v;
    v.x = s4.x + d4.x + ea * k4.x;
    v.y = s4.y + d4.y + ea * k4.y;
    v.z = s4.z + d4.z + ea * k4.z;
    v.w = s4.w + d4.w + ea * k4.w;
    v.x = v.x > 0.f ? v.x : NEG * v.x;
    v.y = v.y > 0.f ? v.y : NEG * v.y;
    v.z = v.z > 0.f ? v.z : NEG * v.z;
    v.w = v.w > 0.f ? v.w : NEG * v.w;
    int pos = atomicAdd(&cursor[dst], 1);
    srcS[pos] = src;
    ((float4*)alS)[pos] = v;
}

// ---------------------------------------------------------------------------
// one wave per dst node: local softmax-max, exp-sum, weighted gather of h[src]
// (fp16, 512B/row), normalize, head-mean, bias, relu, residual. No atomics.
__global__ __launch_bounds__(256) void aggregate_kernel(
    const int* __restrict__ off, const int* __restrict__ srcS,
    const float* __restrict__ alS, const __half* __restrict__ h,
    const float* __restrict__ bias, const float* __restrict__ x,
    float* __restrict__ out, int Nn) {
    int lane = threadIdx.x & 63;
    int n = blockIdx.x * 4 + (threadIdx.x >> 6);
    if (n >= Nn) return;
    int o0 = off[n], o1 = off[n + 1];
    int deg = o1 - o0;

    // phase 1: per-head max over this node's bucket (lane i: edge i>>2, head i&3)
    int sub = lane >> 2, hh = lane & 3;
    float mx = -INFINITY;
    for (int i = sub; i < deg; i += 16)
        mx = fmaxf(mx, alS[(size_t)(o0 + i) * 4 + hh]);
    mx = fmaxf(mx, __shfl_xor(mx, 4));
    mx = fmaxf(mx, __shfl_xor(mx, 8));
    mx = fmaxf(mx, __shfl_xor(mx, 16));
    mx = fmaxf(mx, __shfl_xor(mx, 32));
    int head = lane >> 4;
    float m0 = __shfl(mx, 0), m1 = __shfl(mx, 1), m2 = __shfl(mx, 2), m3 = __shfl(mx, 3);
    float mh = head == 0 ? m0 : head == 1 ? m1 : head == 2 ? m2 : m3;

    // phase 2: exp-weight + gather h rows (512B coalesced per edge)
    const uint2* h2 = (const uint2*)h;  // 4 halves per uint2
    float4 acc = make_float4(0.f, 0.f, 0.f, 0.f);
    float swgt = 0.f;
    int src_n = 0;
    float a_n = 0.f;
    if (deg > 0) {
        src_n = srcS[o0];
        a_n = alS[(size_t)o0 * 4 + head];
    }
#pragma unroll 2
    for (int i = 0; i < deg; ++i) {
        int src = src_n;
        float a = a_n;
        if (i + 1 < deg) {  // prefetch next edge's metadata
            src_n = srcS[o0 + i + 1];
            a_n = alS[(size_t)(o0 + i + 1) * 4 + head];
        }
        float wgt = __expf(a - mh);
        swgt += wgt;
        uint2 hv = h2[(size_t)src * 64 + lane];
        __half2 p01 = *reinterpret_cast<const __half2*>(&hv.x);
        __half2 p23 = *reinterpret_cast<const __half2*>(&hv.y);
        float2 f01 = __half22float2(p01);
        float2 f23 = __half22float2(p23);
        acc.x += wgt * f01.x;
        acc.y += wgt * f01.y;
        acc.z += wgt * f23.x;
        acc.w += wgt * f23.y;
    }
    float inv = 1.f / (swgt + 1e-16f);
    acc.x *= inv; acc.y *= inv; acc.z *= inv; acc.w *= inv;

    // head-mean: sum lanes {l, l^16, l^32, l^48} (same channels, different heads)
    acc.x += __shfl_xor(acc.x, 16);
    acc.y += __shfl_xor(acc.y, 16);
    acc.z += __shfl_xor(acc.z, 16);
    acc.w += __shfl_xor(acc.w, 16);
    acc.x += __shfl_xor(acc.x, 32);
    acc.y += __shfl_xor(acc.y, 32);
    acc.z += __shfl_xor(acc.z, 32);
    acc.w += __shfl_xor(acc.w, 32);
    if (lane < 16) {
        float4 b = ((const float4*)bias)[lane];
        float4 xv = ((const float4*)x)[(size_t)n * 16 + lane];
        float4 o;
        o.x = fmaxf(acc.x * 0.25f + b.x, 0.f) + xv.x;
        o.y = fmaxf(acc.y * 0.25f + b.y, 0.f) + xv.y;
        o.z = fmaxf(acc.z * 0.25f + b.z, 0.f) + xv.z;
        o.w = fmaxf(acc.w * 0.25f + b.w, 0.f) + xv.w;
        ((float4*)out)[(size_t)n * 16 + lane] = o;
    }
}

// ---------------------------------------------------------------------------
extern "C" void kernel_launch(void* const* d_in, const int* in_sizes, int n_in,
                              void* d_out, int out_size, void* d_ws, size_t ws_size,
                              hipStream_t stream) {
    const float* x = (const float*)d_in[0];
    const int* ei = (const int*)d_in[1];
    const float* edge_attr = (const float*)d_in[2];
    const float* W = (const float*)d_in[3];
    const float* att_src = (const float*)d_in[4];
    const float* att_dst = (const float*)d_in[5];
    const float* lin_edge_w = (const float*)d_in[6];
    const float* att_edge = (const float*)d_in[7];
    const float* bias = (const float*)d_in[8];
    float* out = (float*)d_out;
    int Nn = in_sizes[0] / 64;
    int Ee = in_sizes[1] / 2;
    int tot = Ee + Nn;
    int numBlocks = (Nn + 255) / 256;  // 196 for N=50000; scan2 handles <=256

    char* p = (char*)d_ws;
    size_t o = 0;
    auto alloc = [&](size_t bytes) -> char* {
        char* r = p + o;
        o += (bytes + 255) & ~(size_t)255;
        return r;
    };
    float* mean_acc = (float*)alloc(256);               // zeroed below
    int* counts = (int*)alloc((size_t)Nn * 4);          // zeroed below
    size_t zero_bytes = o;
    float* Kh = (float*)alloc(256);                     // [H]
    int* blockSums = (int*)alloc((size_t)numBlocks * 4);
    int* blockOff = (int*)alloc((size_t)numBlocks * 4);
    int* off = (int*)alloc((size_t)(Nn + 1) * 4);       // [N+1] CSR offsets
    int* cursor = (int*)alloc((size_t)Nn * 4);          // [N] bucket cursors
    int* srcS = (int*)alloc((size_t)tot * 4);           // [tot] src sorted by dst
    float* alS = (float*)alloc((size_t)tot * H * 4);    // [tot][H] logits sorted by dst
    __half* h = (__half*)alloc((size_t)Nn * HC * 2);    // [N,H,C] fp16
    float* a_src = (float*)alloc((size_t)Nn * H * 4);
    float* a_dst = (float*)alloc((size_t)Nn * H * 4);
    (void)ws_size;

    hipMemsetAsync(d_ws, 0, zero_bytes, stream);
    init_kernel<<<512, 256, 0, stream>>>(ei, edge_attr, lin_edge_w, att_edge,
                                         counts, mean_acc, Kh, Ee);
    gemm_kernel<<<2048, 256, 0, stream>>>(x, W, att_src, att_dst, h, a_src, a_dst, Nn);
    scan1_kernel<<<numBlocks, 256, 0, stream>>>(counts, blockSums, Nn);
    scan2_kernel<<<1, 256, 0, stream>>>(blockSums, blockOff, off, numBlocks, Nn);
    scan3_kernel<<<numBlocks, 256, 0, stream>>>(counts, blockOff, off, cursor, Nn);
    sortscatter_kernel<<<(tot + 255) / 256, 256, 0, stream>>>(
        ei, edge_attr, a_src, a_dst, mean_acc, Kh, cursor, srcS, alS, Nn, Ee);
    aggregate_kernel<<<(Nn + 3) / 4, 256, 0, stream>>>(off, srcS, alS, h, bias, x, out, Nn);
}